// Round 6
// baseline (196.159 us; speedup 1.0000x reference)
//
#include <hip/hip_runtime.h>
#include <hip/hip_bf16.h>
#include <math.h>

#define N 4096
#define D 128
#define NB 16  // N / 256 column blocks
#define POS_W 2.0f
#define NEG_W 40.0f
#define MARGIN 0.1f
#define THRESH 0.5f

typedef __bf16 bf16x8 __attribute__((ext_vector_type(8)));
typedef float f32x4 __attribute__((ext_vector_type(4)));

// ctrs layout (unsigned words): [0..15]=ctr1 (pass0 done per ib),
// [16..31]=ctr2 (exp partials done per ib), [32]=ctr3, [33..35]=g_sums (float)

// ---------------- K1: L2-normalize rows -> bf16; zero semaphores ----------------
__global__ __launch_bounds__(512) void k_norm(const float* __restrict__ x,
                                              ushort* __restrict__ xn,
                                              unsigned int* __restrict__ ctrs) {
  const int t = threadIdx.x, wv = t >> 6, lane = t & 63;
  if (blockIdx.x == 0 && t < 64) ctrs[t] = 0u;
#pragma unroll
  for (int rr = 0; rr < 2; ++rr) {
    const int row = blockIdx.x * 16 + wv * 2 + rr;
    const float2 v = *(const float2*)&x[row * D + lane * 2];
    float ss = v.x * v.x + v.y * v.y;
#pragma unroll
    for (int off = 32; off; off >>= 1) ss += __shfl_xor(ss, off);
    const float rnorm = rsqrtf(ss);
    __hip_bfloat162 o;
    o.x = __float2bfloat16(v.x * rnorm);
    o.y = __float2bfloat16(v.y * rnorm);
    *(__hip_bfloat162*)&xn[row * D + lane * 2] = o;
  }
}

// ---------------- K2: one matmul, S in registers across both mining phases ----------------
// Cooperative launch (co-residency guarantee) but NO grid.sync — per-row-group
// semaphores instead. 256 blocks, 1/CU.
__global__ __launch_bounds__(512, 2) void k_mega(
    const ushort* __restrict__ xn, const int* __restrict__ labels,
    float* __restrict__ pminPart, float* __restrict__ nmaxPart,
    float* __restrict__ ppPart, float* __restrict__ npPart,
    unsigned int* __restrict__ ctrs, float* __restrict__ out) {
  __shared__ ushort Abuf[256 * 128];  // 64 KB bf16 [row][k], XOR-swizzled
  __shared__ ushort Bbuf[256 * 128];  // 64 KB
  __shared__ int labi[256], labj[256];
  __shared__ float redA[256][4], redB[256][4];
  __shared__ float mpS[256], mnS[256];
  __shared__ float fin[3][8];

  unsigned int* ctr1 = ctrs;
  unsigned int* ctr2 = ctrs + 16;
  unsigned int* ctr3 = ctrs + 32;
  float* g_sums = (float*)(ctrs + 33);

  const int t = threadIdx.x;
  const int lane = t & 63;
  const int ib = blockIdx.x >> 4, jb = blockIdx.x & 15;
  const int i0 = ib * 256, j0 = jb * 256;

  if (t < 256) {
    labi[t] = labels[i0 + t];
    labj[t] = labels[j0 + t];
  }
  // stage tiles: linear global reads, swizzled LDS writes
  {
    const char* gA = (const char*)(xn + (size_t)i0 * D);
    const char* gB = (const char*)(xn + (size_t)j0 * D);
#pragma unroll
    for (int it = 0; it < 8; ++it) {
      const int L = (t + it * 512) * 16;         // linear byte offset in 64KB tile
      const int Ls = L ^ (((L >> 8) & 7) << 4);  // row-XOR bank swizzle
      *(f32x4*)((char*)Abuf + Ls) = *(const f32x4*)(gA + L);
      *(f32x4*)((char*)Bbuf + Ls) = *(const f32x4*)(gB + L);
    }
  }
  __syncthreads();

  const int w = t >> 6;
  const int wm = w >> 2, wn = w & 3;  // 2 x 4 wave grid; wave owns 128x64
  const int lr = lane & 15, lk = lane >> 4;

  f32x4 acc[8][4];
#pragma unroll
  for (int m = 0; m < 8; ++m)
#pragma unroll
    for (int n = 0; n < 4; ++n) acc[m][n] = (f32x4){0.f, 0.f, 0.f, 0.f};

#pragma unroll
  for (int ks = 0; ks < 4; ++ks) {
    bf16x8 af[8], bg[4];
#pragma unroll
    for (int m = 0; m < 8; ++m) {
      const int rowb = wm * 128 + m * 16 + lr;
      int off = rowb * 256 + ks * 64 + lk * 16;
      off ^= ((rowb & 7) << 4);
      af[m] = *(const bf16x8*)((const char*)Abuf + off);
    }
#pragma unroll
    for (int n = 0; n < 4; ++n) {
      const int rowb = wn * 64 + n * 16 + lr;
      int off = rowb * 256 + ks * 64 + lk * 16;
      off ^= ((rowb & 7) << 4);
      bg[n] = *(const bf16x8*)((const char*)Bbuf + off);
    }
#pragma unroll
    for (int m = 0; m < 8; ++m)
#pragma unroll
      for (int n = 0; n < 4; ++n)
        acc[m][n] = __builtin_amdgcn_mfma_f32_16x16x32_bf16(af[m], bg[n], acc[m][n], 0, 0, 0);
  }

  // C layout: col = lane&15 (B-row), row = (lane>>4)*4 + reg (A-row)
  int ljr[4];
#pragma unroll
  for (int n = 0; n < 4; ++n) ljr[n] = labj[wn * 64 + n * 16 + lr];

  // ---------- phase B: min_pos / max_neg epilogue -> disjoint partials ----------
#pragma unroll
  for (int m = 0; m < 8; ++m) {
#pragma unroll
    for (int r = 0; r < 4; ++r) {
      const int rl = wm * 128 + m * 16 + lk * 4 + r;
      const int li = labi[rl];
      const int gi = i0 + rl;
      float pmin = 1e9f, nmax = -1e9f;
#pragma unroll
      for (int n = 0; n < 4; ++n) {
        const int cl = wn * 64 + n * 16 + lr;
        const float s = acc[m][n][r];
        if (ljr[n] == li) {
          if (gi != j0 + cl) pmin = fminf(pmin, s);
        } else {
          nmax = fmaxf(nmax, s);
        }
      }
#pragma unroll
      for (int o = 1; o < 16; o <<= 1) {
        pmin = fminf(pmin, __shfl_xor(pmin, o));
        nmax = fmaxf(nmax, __shfl_xor(nmax, o));
      }
      if (lr == 0) { redA[rl][wn] = pmin; redB[rl][wn] = nmax; }
    }
  }
  __syncthreads();
  if (t < 256) {
    pminPart[jb * N + i0 + t] =
        fminf(fminf(redA[t][0], redA[t][1]), fminf(redA[t][2], redA[t][3]));
    nmaxPart[jb * N + i0 + t] =
        fmaxf(fmaxf(redB[t][0], redB[t][1]), fmaxf(redB[t][2], redB[t][3]));
  }
  __threadfence();  // make partials visible at agent scope
  __syncthreads();
  if (t == 0) __hip_atomic_fetch_add(&ctr1[ib], 1u, __ATOMIC_RELAXED, __HIP_MEMORY_SCOPE_AGENT);

  // ---------- semaphore: wait for all 16 column-blocks of row group ib ----------
  if (t == 0) {
    while (__hip_atomic_load(&ctr1[ib], __ATOMIC_RELAXED, __HIP_MEMORY_SCOPE_AGENT) != 16u)
      __builtin_amdgcn_s_sleep(2);
    __threadfence();  // acquire: invalidate caches before reading partials
  }
  __syncthreads();

  // ---------- phase C: reduce partials -> thresholds ----------
  if (t < 256) {
    float mp = 1e9f, mx = -1e9f;
#pragma unroll
    for (int b = 0; b < NB; ++b) {
      mp = fminf(mp, pminPart[b * N + i0 + t]);
      mx = fmaxf(mx, nmaxPart[b * N + i0 + t]);
    }
    mpS[t] = mp;
    mnS[t] = mx;
  }
  __syncthreads();

  // ---------- phase D: mined exp sums over the SAME registers ----------
#pragma unroll
  for (int m = 0; m < 8; ++m) {
#pragma unroll
    for (int r = 0; r < 4; ++r) {
      const int rl = wm * 128 + m * 16 + lk * 4 + r;
      const int li = labi[rl];
      const int gi = i0 + rl;
      const float mp = mpS[rl], mx = mnS[rl];
      float psum = 0.f, nsum = 0.f;
#pragma unroll
      for (int n = 0; n < 4; ++n) {
        const int cl = wn * 64 + n * 16 + lr;
        const float s = acc[m][n][r];
        if (ljr[n] == li) {
          if ((gi != j0 + cl) && (s - MARGIN < mx)) psum += __expf(-POS_W * (s - THRESH));
        } else {
          if (s + MARGIN > mp) nsum += __expf(NEG_W * (s - THRESH));
        }
      }
#pragma unroll
      for (int o = 1; o < 16; o <<= 1) {
        psum += __shfl_xor(psum, o);
        nsum += __shfl_xor(nsum, o);
      }
      if (lr == 0) { redA[rl][wn] = psum; redB[rl][wn] = nsum; }
    }
  }
  __syncthreads();
  if (t < 256) {
    ppPart[jb * N + i0 + t] = redA[t][0] + redA[t][1] + redA[t][2] + redA[t][3];
    npPart[jb * N + i0 + t] = redB[t][0] + redB[t][1] + redB[t][2] + redB[t][3];
  }
  __threadfence();
  __syncthreads();
  if (t == 0) __hip_atomic_fetch_add(&ctr2[ib], 1u, __ATOMIC_RELAXED, __HIP_MEMORY_SCOPE_AGENT);

  // ---------- phase E: row terms + final (one block per row group) ----------
  if (jb != 0) return;

  if (t == 0) {
    while (__hip_atomic_load(&ctr2[ib], __ATOMIC_RELAXED, __HIP_MEMORY_SCOPE_AGENT) != 16u)
      __builtin_amdgcn_s_sleep(2);
    __threadfence();
  }
  __syncthreads();

  float sp = 0.f, sn = 0.f, sc = 0.f;
  if (t < 256) {
    float ps = 0.f, ns = 0.f;
#pragma unroll
    for (int b = 0; b < NB; ++b) {
      ps += ppPart[b * N + i0 + t];
      ns += npPart[b * N + i0 + t];
    }
    const float mp = mpS[t], mx = mnS[t];
    const bool valid = (mp < 1e8f) && (mx > -1e8f) && (ps > 0.f) && (ns > 0.f);
    if (valid) {
      sp = log1pf(ps) * (1.0f / POS_W);
      sn = log1pf(ns) * (1.0f / NEG_W);
      sc = 1.f;
    }
  }
#pragma unroll
  for (int off = 32; off; off >>= 1) {
    sp += __shfl_xor(sp, off);
    sn += __shfl_xor(sn, off);
    sc += __shfl_xor(sc, off);
  }
  if (lane == 0) { fin[0][w] = sp; fin[1][w] = sn; fin[2][w] = sc; }
  __syncthreads();
  if (t == 0) {
    float tp = 0.f, tn = 0.f, tc = 0.f;
#pragma unroll
    for (int k = 0; k < 8; ++k) { tp += fin[0][k]; tn += fin[1][k]; tc += fin[2][k]; }
    atomicAdd(&g_sums[0], tp);
    atomicAdd(&g_sums[1], tn);
    atomicAdd(&g_sums[2], tc);
    __threadfence();
    const unsigned int prev =
        __hip_atomic_fetch_add(ctr3, 1u, __ATOMIC_RELAXED, __HIP_MEMORY_SCOPE_AGENT);
    if (prev == 15u) {  // last row-group finalizes
      __threadfence();
      const float tpA = __hip_atomic_load(&g_sums[0], __ATOMIC_RELAXED, __HIP_MEMORY_SCOPE_AGENT);
      const float tnA = __hip_atomic_load(&g_sums[1], __ATOMIC_RELAXED, __HIP_MEMORY_SCOPE_AGENT);
      const float tcA = __hip_atomic_load(&g_sums[2], __ATOMIC_RELAXED, __HIP_MEMORY_SCOPE_AGENT);
      const float cnt = fmaxf(tcA, 1.f);
      const float pm = tpA / cnt, nm = tnA / cnt;
      out[0] = pm + nm;
      out[1] = pm;
      out[2] = nm;
    }
  }
}

extern "C" void kernel_launch(void* const* d_in, const int* in_sizes, int n_in,
                              void* d_out, int out_size, void* d_ws, size_t ws_size,
                              hipStream_t stream) {
  const float* batch = (const float*)d_in[0];
  const int* labels = (const int*)d_in[1];
  float* out = (float*)d_out;

  char* ws = (char*)d_ws;
  ushort* xn = (ushort*)ws;                            // N*D bf16 = 1 MB
  float* pminPart = (float*)(ws + (size_t)N * D * 2);  // NB*N
  float* nmaxPart = pminPart + (size_t)NB * N;         // NB*N
  float* ppPart = nmaxPart + (size_t)NB * N;           // NB*N
  float* npPart = ppPart + (size_t)NB * N;             // NB*N
  unsigned int* ctrs = (unsigned int*)(npPart + (size_t)NB * N);  // 64 words

  k_norm<<<N / 16, 512, 0, stream>>>(batch, xn, ctrs);

  void* args[] = {(void*)&xn,     (void*)&labels, (void*)&pminPart, (void*)&nmaxPart,
                  (void*)&ppPart, (void*)&npPart, (void*)&ctrs,     (void*)&out};
  hipLaunchCooperativeKernel((const void*)k_mega, dim3(256), dim3(512), args, 0, stream);
}

// Round 11
// 112.054 us; speedup vs baseline: 1.7506x; 1.7506x over previous
//
#include <hip/hip_runtime.h>
#include <hip/hip_bf16.h>
#include <math.h>

#define N 4096
#define D 128
#define R 16  // rows per block (one 16-row m-tile)
#define POS_W 2.0f
#define NEG_W 40.0f
#define MARGIN 0.1f
#define THRESH 0.5f

typedef __bf16 bf16x8 __attribute__((ext_vector_type(8)));
typedef float f32x4 __attribute__((ext_vector_type(4)));

// ---------------- K1: L2-normalize rows -> bf16 ----------------
__global__ __launch_bounds__(512) void k_norm(const float* __restrict__ x,
                                              ushort* __restrict__ xn) {
  const int t = threadIdx.x, wv = t >> 6, lane = t & 63;
#pragma unroll
  for (int rr = 0; rr < 2; ++rr) {
    const int row = blockIdx.x * 16 + wv * 2 + rr;
    const float2 v = *(const float2*)&x[row * D + lane * 2];
    float ss = v.x * v.x + v.y * v.y;
#pragma unroll
    for (int off = 32; off; off >>= 1) ss += __shfl_xor(ss, off);
    const float rnorm = rsqrtf(ss);
    __hip_bfloat162 o;
    o.x = __float2bfloat16(v.x * rnorm);
    o.y = __float2bfloat16(v.y * rnorm);
    *(__hip_bfloat162*)&xn[row * D + lane * 2] = o;
  }
}

// ---------------- K2: full row-stripe per block; everything block-local ----------------
// Block b owns rows i0=b*16 .. i0+15 vs ALL N cols. Wave wv owns cols wv*512..+511.
// S stripe stays in registers across both mining phases. No cross-block deps.
__global__ __launch_bounds__(512, 2) void k_mega(const ushort* __restrict__ xn,
                                                 const int* __restrict__ labels,
                                                 float* __restrict__ row_pos,
                                                 float* __restrict__ row_neg,
                                                 float* __restrict__ row_valid) {
  __shared__ int labs[N];  // 16 KB: all labels
  __shared__ float redA[8][R], redB[8][R];
  __shared__ float mpS[R], mnS[R];

  const int t = threadIdx.x;
  const int wv = t >> 6, lane = t & 63;
  const int lk = lane >> 4, lr = lane & 15;
  const int i0 = blockIdx.x * R;

  // stage all labels into LDS (coalesced int4)
#pragma unroll
  for (int it = 0; it < 2; ++it)
    ((int4*)labs)[t + it * 512] = ((const int4*)labels)[t + it * 512];
  __syncthreads();

  // A fragments: A-row = lr (block row), k-chunk = ks*32 + lk*8  (direct from L2)
  bf16x8 af[4];
#pragma unroll
  for (int ks = 0; ks < 4; ++ks)
    af[ks] = *(const bf16x8*)&xn[(i0 + lr) * D + ks * 32 + lk * 8];

  // ---- matmul: 32 n-tiles x 4 k-steps; B-frag streamed from L2 ----
  const int jbase = wv * 512 + lr;  // this lane's B-row for n-tile n: jbase + n*16
  f32x4 acc[32];
#pragma unroll
  for (int n = 0; n < 32; ++n) acc[n] = (f32x4){0.f, 0.f, 0.f, 0.f};

#pragma unroll
  for (int n = 0; n < 32; ++n) {
    const ushort* bp = &xn[(size_t)(jbase + n * 16) * D + lk * 8];
    const bf16x8 b0 = *(const bf16x8*)(bp);
    const bf16x8 b1 = *(const bf16x8*)(bp + 32);
    const bf16x8 b2 = *(const bf16x8*)(bp + 64);
    const bf16x8 b3 = *(const bf16x8*)(bp + 96);
    acc[n] = __builtin_amdgcn_mfma_f32_16x16x32_bf16(af[0], b0, acc[n], 0, 0, 0);
    acc[n] = __builtin_amdgcn_mfma_f32_16x16x32_bf16(af[1], b1, acc[n], 0, 0, 0);
    acc[n] = __builtin_amdgcn_mfma_f32_16x16x32_bf16(af[2], b2, acc[n], 0, 0, 0);
    acc[n] = __builtin_amdgcn_mfma_f32_16x16x32_bf16(af[3], b3, acc[n], 0, 0, 0);
  }

  // C layout: col = lr (B-row), rows = lk*4 + r (A-rows), r = reg 0..3
  int labr[4];
  int girow[4];
#pragma unroll
  for (int r = 0; r < 4; ++r) {
    girow[r] = i0 + lk * 4 + r;
    labr[r] = labs[girow[r]];
  }

  // ---- phase 1: per-row min_pos / max_neg (block-local) ----
  float pmin[4] = {1e9f, 1e9f, 1e9f, 1e9f};
  float nmax[4] = {-1e9f, -1e9f, -1e9f, -1e9f};
#pragma unroll
  for (int n = 0; n < 32; ++n) {
    const int j = jbase + n * 16;
    const int lj = labs[j];
#pragma unroll
    for (int r = 0; r < 4; ++r) {
      const float s = acc[n][r];
      if (lj == labr[r]) {
        if (girow[r] != j) pmin[r] = fminf(pmin[r], s);
      } else {
        nmax[r] = fmaxf(nmax[r], s);
      }
    }
  }
#pragma unroll
  for (int o = 1; o < 16; o <<= 1) {
#pragma unroll
    for (int r = 0; r < 4; ++r) {
      pmin[r] = fminf(pmin[r], __shfl_xor(pmin[r], o));
      nmax[r] = fmaxf(nmax[r], __shfl_xor(nmax[r], o));
    }
  }
  if (lr == 0) {
#pragma unroll
    for (int r = 0; r < 4; ++r) {
      redA[wv][lk * 4 + r] = pmin[r];
      redB[wv][lk * 4 + r] = nmax[r];
    }
  }
  __syncthreads();
  if (t < R) {
    float mp = 1e9f, mx = -1e9f;
#pragma unroll
    for (int wvv = 0; wvv < 8; ++wvv) {
      mp = fminf(mp, redA[wvv][t]);
      mx = fmaxf(mx, redB[wvv][t]);
    }
    mpS[t] = mp;
    mnS[t] = mx;
  }
  __syncthreads();

  // ---- phase 2: mined exp sums over the SAME registers ----
  float mpr[4], mxr[4];
#pragma unroll
  for (int r = 0; r < 4; ++r) {
    mpr[r] = mpS[lk * 4 + r];
    mxr[r] = mnS[lk * 4 + r];
  }
  float psum[4] = {0.f, 0.f, 0.f, 0.f};
  float nsum[4] = {0.f, 0.f, 0.f, 0.f};
#pragma unroll
  for (int n = 0; n < 32; ++n) {
    const int j = jbase + n * 16;
    const int lj = labs[j];
#pragma unroll
    for (int r = 0; r < 4; ++r) {
      const float s = acc[n][r];
      if (lj == labr[r]) {
        if ((girow[r] != j) && (s - MARGIN < mxr[r])) psum[r] += __expf(-POS_W * (s - THRESH));
      } else {
        if (s + MARGIN > mpr[r]) nsum[r] += __expf(NEG_W * (s - THRESH));
      }
    }
  }
#pragma unroll
  for (int o = 1; o < 16; o <<= 1) {
#pragma unroll
    for (int r = 0; r < 4; ++r) {
      psum[r] += __shfl_xor(psum[r], o);
      nsum[r] += __shfl_xor(nsum[r], o);
    }
  }
  if (lr == 0) {
#pragma unroll
    for (int r = 0; r < 4; ++r) {
      redA[wv][lk * 4 + r] = psum[r];
      redB[wv][lk * 4 + r] = nsum[r];
    }
  }
  __syncthreads();

  // ---- row terms (block-local) ----
  if (t < R) {
    float ps = 0.f, ns = 0.f;
#pragma unroll
    for (int wvv = 0; wvv < 8; ++wvv) {
      ps += redA[wvv][t];
      ns += redB[wvv][t];
    }
    const float mp = mpS[t], mx = mnS[t];
    const bool valid = (mp < 1e8f) && (mx > -1e8f) && (ps > 0.f) && (ns > 0.f);
    row_pos[i0 + t] = valid ? (log1pf(ps) * (1.0f / POS_W)) : 0.f;
    row_neg[i0 + t] = valid ? (log1pf(ns) * (1.0f / NEG_W)) : 0.f;
    row_valid[i0 + t] = valid ? 1.f : 0.f;
  }
}

// ---------------- K3: final reduction ----------------
__global__ __launch_bounds__(256) void k_final(const float* __restrict__ rp,
                                               const float* __restrict__ rn,
                                               const float* __restrict__ rv,
                                               float* __restrict__ out) {
  __shared__ float red[3][4];
  const int t = threadIdx.x, wv = t >> 6, lane = t & 63;
  float sp = 0.f, sn = 0.f, sc = 0.f;
  for (int i = t; i < N; i += 256) { sp += rp[i]; sn += rn[i]; sc += rv[i]; }
#pragma unroll
  for (int off = 32; off; off >>= 1) {
    sp += __shfl_xor(sp, off);
    sn += __shfl_xor(sn, off);
    sc += __shfl_xor(sc, off);
  }
  if (lane == 0) { red[0][wv] = sp; red[1][wv] = sn; red[2][wv] = sc; }
  __syncthreads();
  if (t == 0) {
    const float tp = red[0][0] + red[0][1] + red[0][2] + red[0][3];
    const float tn = red[1][0] + red[1][1] + red[1][2] + red[1][3];
    const float tc = red[2][0] + red[2][1] + red[2][2] + red[2][3];
    const float cnt = fmaxf(tc, 1.f);
    const float pm = tp / cnt, nm = tn / cnt;
    out[0] = pm + nm;
    out[1] = pm;
    out[2] = nm;
  }
}

extern "C" void kernel_launch(void* const* d_in, const int* in_sizes, int n_in,
                              void* d_out, int out_size, void* d_ws, size_t ws_size,
                              hipStream_t stream) {
  const float* batch = (const float*)d_in[0];
  const int* labels = (const int*)d_in[1];
  float* out = (float*)d_out;

  char* ws = (char*)d_ws;
  ushort* xn = (ushort*)ws;                       // N*D bf16 = 1 MB
  float* row_pos = (float*)(ws + (size_t)N * D * 2);
  float* row_neg = row_pos + N;
  float* row_valid = row_neg + N;

  k_norm<<<N / 16, 512, 0, stream>>>(batch, xn);
  k_mega<<<N / R, 512, 0, stream>>>(xn, labels, row_pos, row_neg, row_valid);
  k_final<<<1, 256, 0, stream>>>(row_pos, row_neg, row_valid, out);
}

// Round 12
// 92.205 us; speedup vs baseline: 2.1274x; 1.2153x over previous
//
#include <hip/hip_runtime.h>
#include <hip/hip_bf16.h>
#include <math.h>

#define N 4096
#define D 128
#define R 16  // rows per block (one 16-row m-tile)
#define POS_W 2.0f
#define NEG_W 40.0f
#define MARGIN 0.1f
#define THRESH 0.5f

typedef __bf16 bf16x8 __attribute__((ext_vector_type(8)));
typedef float f32x4 __attribute__((ext_vector_type(4)));

// Packed operand layout (ushort units):
//   xp[g][ks][lane][e]  ->  g*4096 + ks*512 + lane*8 + e
// where g = row>>4 (16-row group), lane = lk*16 + lr (lr=row&15, lk=k-subchunk),
// element (row, k) with k = ks*32 + lk*8 + e.  A wave's MFMA fragment for
// (group g, k-step ks) is ONE fully-contiguous 1KB load: base + lane*16B.

// ---------------- K1: L2-normalize rows -> bf16, write MFMA-packed layout ----------------
__global__ __launch_bounds__(512) void k_norm(const float* __restrict__ x,
                                              ushort* __restrict__ xp) {
  const int t = threadIdx.x, wv = t >> 6, lane = t & 63;
#pragma unroll
  for (int rr = 0; rr < 2; ++rr) {
    const int row = blockIdx.x * 16 + wv * 2 + rr;
    const float2 v = *(const float2*)&x[row * D + lane * 2];
    float ss = v.x * v.x + v.y * v.y;
#pragma unroll
    for (int off = 32; off; off >>= 1) ss += __shfl_xor(ss, off);
    const float rnorm = rsqrtf(ss);
    __hip_bfloat162 o;
    o.x = __float2bfloat16(v.x * rnorm);
    o.y = __float2bfloat16(v.y * rnorm);
    // k0 = lane*2: ks = lane>>4, lk = (lane>>2)&3, e = (lane*2)&7
    const int g = row >> 4, lr = row & 15;
    const int ks = lane >> 4, lk = (lane >> 2) & 3, e = (lane & 3) * 2;
    const int idx = g * 4096 + ks * 512 + (lk * 16 + lr) * 8 + e;
    *(__hip_bfloat162*)&xp[idx] = o;
  }
}

// ---------------- K2: full row-stripe per block; everything block-local ----------------
// Block b owns rows i0=b*16 .. i0+15 vs ALL N cols. Wave wv owns cols wv*512..+511.
// S stripe stays in registers across both mining phases. No cross-block deps.
// All operand loads are contiguous 1KB wave loads from the packed layout.
__global__ __launch_bounds__(512, 2) void k_mega(const ushort* __restrict__ xp,
                                                 const int* __restrict__ labels,
                                                 float* __restrict__ row_pos,
                                                 float* __restrict__ row_neg,
                                                 float* __restrict__ row_valid) {
  __shared__ int labs[N];  // 16 KB: all labels
  __shared__ float redA[8][R], redB[8][R];
  __shared__ float mpS[R], mnS[R];

  const int t = threadIdx.x;
  const int wv = t >> 6, lane = t & 63;
  const int lk = lane >> 4, lr = lane & 15;
  const int i0 = blockIdx.x * R;

  // stage all labels into LDS (coalesced int4)
#pragma unroll
  for (int it = 0; it < 2; ++it)
    ((int4*)labs)[t + it * 512] = ((const int4*)labels)[t + it * 512];
  __syncthreads();

  // A fragments: group g = blockIdx.x; one contiguous 1KB load per ks
  bf16x8 af[4];
#pragma unroll
  for (int ks = 0; ks < 4; ++ks)
    af[ks] = *(const bf16x8*)&xp[blockIdx.x * 4096 + ks * 512 + lane * 8];

  // ---- matmul: 32 n-tiles x 4 k-steps; B-frags are contiguous 1KB wave loads ----
  const int jbase = wv * 512 + lr;  // this lane's B-row for n-tile n: jbase + n*16
  f32x4 acc[32];
#pragma unroll
  for (int n = 0; n < 32; ++n) acc[n] = (f32x4){0.f, 0.f, 0.f, 0.f};

#pragma unroll
  for (int n = 0; n < 32; ++n) {
    const ushort* bp = &xp[(wv * 32 + n) * 4096 + lane * 8];
    const bf16x8 b0 = *(const bf16x8*)(bp);
    const bf16x8 b1 = *(const bf16x8*)(bp + 512);
    const bf16x8 b2 = *(const bf16x8*)(bp + 1024);
    const bf16x8 b3 = *(const bf16x8*)(bp + 1536);
    acc[n] = __builtin_amdgcn_mfma_f32_16x16x32_bf16(af[0], b0, acc[n], 0, 0, 0);
    acc[n] = __builtin_amdgcn_mfma_f32_16x16x32_bf16(af[1], b1, acc[n], 0, 0, 0);
    acc[n] = __builtin_amdgcn_mfma_f32_16x16x32_bf16(af[2], b2, acc[n], 0, 0, 0);
    acc[n] = __builtin_amdgcn_mfma_f32_16x16x32_bf16(af[3], b3, acc[n], 0, 0, 0);
  }

  // C layout: col = lr (B-row), rows = lk*4 + r (A-rows), r = reg 0..3
  int labr[4];
  int girow[4];
#pragma unroll
  for (int r = 0; r < 4; ++r) {
    girow[r] = i0 + lk * 4 + r;
    labr[r] = labs[girow[r]];
  }

  // ---- phase 1: per-row min_pos / max_neg (block-local) ----
  float pmin[4] = {1e9f, 1e9f, 1e9f, 1e9f};
  float nmax[4] = {-1e9f, -1e9f, -1e9f, -1e9f};
#pragma unroll
  for (int n = 0; n < 32; ++n) {
    const int j = jbase + n * 16;
    const int lj = labs[j];
#pragma unroll
    for (int r = 0; r < 4; ++r) {
      const float s = acc[n][r];
      if (lj == labr[r]) {
        if (girow[r] != j) pmin[r] = fminf(pmin[r], s);
      } else {
        nmax[r] = fmaxf(nmax[r], s);
      }
    }
  }
#pragma unroll
  for (int o = 1; o < 16; o <<= 1) {
#pragma unroll
    for (int r = 0; r < 4; ++r) {
      pmin[r] = fminf(pmin[r], __shfl_xor(pmin[r], o));
      nmax[r] = fmaxf(nmax[r], __shfl_xor(nmax[r], o));
    }
  }
  if (lr == 0) {
#pragma unroll
    for (int r = 0; r < 4; ++r) {
      redA[wv][lk * 4 + r] = pmin[r];
      redB[wv][lk * 4 + r] = nmax[r];
    }
  }
  __syncthreads();
  if (t < R) {
    float mp = 1e9f, mx = -1e9f;
#pragma unroll
    for (int wvv = 0; wvv < 8; ++wvv) {
      mp = fminf(mp, redA[wvv][t]);
      mx = fmaxf(mx, redB[wvv][t]);
    }
    mpS[t] = mp;
    mnS[t] = mx;
  }
  __syncthreads();

  // ---- phase 2: mined exp sums over the SAME registers ----
  float mpr[4], mxr[4];
#pragma unroll
  for (int r = 0; r < 4; ++r) {
    mpr[r] = mpS[lk * 4 + r];
    mxr[r] = mnS[lk * 4 + r];
  }
  float psum[4] = {0.f, 0.f, 0.f, 0.f};
  float nsum[4] = {0.f, 0.f, 0.f, 0.f};
#pragma unroll
  for (int n = 0; n < 32; ++n) {
    const int j = jbase + n * 16;
    const int lj = labs[j];
#pragma unroll
    for (int r = 0; r < 4; ++r) {
      const float s = acc[n][r];
      if (lj == labr[r]) {
        if ((girow[r] != j) && (s - MARGIN < mxr[r])) psum[r] += __expf(-POS_W * (s - THRESH));
      } else {
        if (s + MARGIN > mpr[r]) nsum[r] += __expf(NEG_W * (s - THRESH));
      }
    }
  }
#pragma unroll
  for (int o = 1; o < 16; o <<= 1) {
#pragma unroll
    for (int r = 0; r < 4; ++r) {
      psum[r] += __shfl_xor(psum[r], o);
      nsum[r] += __shfl_xor(nsum[r], o);
    }
  }
  if (lr == 0) {
#pragma unroll
    for (int r = 0; r < 4; ++r) {
      redA[wv][lk * 4 + r] = psum[r];
      redB[wv][lk * 4 + r] = nsum[r];
    }
  }
  __syncthreads();

  // ---- row terms (block-local) ----
  if (t < R) {
    float ps = 0.f, ns = 0.f;
#pragma unroll
    for (int wvv = 0; wvv < 8; ++wvv) {
      ps += redA[wvv][t];
      ns += redB[wvv][t];
    }
    const float mp = mpS[t], mx = mnS[t];
    const bool valid = (mp < 1e8f) && (mx > -1e8f) && (ps > 0.f) && (ns > 0.f);
    row_pos[i0 + t] = valid ? (log1pf(ps) * (1.0f / POS_W)) : 0.f;
    row_neg[i0 + t] = valid ? (log1pf(ns) * (1.0f / NEG_W)) : 0.f;
    row_valid[i0 + t] = valid ? 1.f : 0.f;
  }
}

// ---------------- K3: final reduction ----------------
__global__ __launch_bounds__(256) void k_final(const float* __restrict__ rp,
                                               const float* __restrict__ rn,
                                               const float* __restrict__ rv,
                                               float* __restrict__ out) {
  __shared__ float red[3][4];
  const int t = threadIdx.x, wv = t >> 6, lane = t & 63;
  float sp = 0.f, sn = 0.f, sc = 0.f;
  for (int i = t; i < N; i += 256) { sp += rp[i]; sn += rn[i]; sc += rv[i]; }
#pragma unroll
  for (int off = 32; off; off >>= 1) {
    sp += __shfl_xor(sp, off);
    sn += __shfl_xor(sn, off);
    sc += __shfl_xor(sc, off);
  }
  if (lane == 0) { red[0][wv] = sp; red[1][wv] = sn; red[2][wv] = sc; }
  __syncthreads();
  if (t == 0) {
    const float tp = red[0][0] + red[0][1] + red[0][2] + red[0][3];
    const float tn = red[1][0] + red[1][1] + red[1][2] + red[1][3];
    const float tc = red[2][0] + red[2][1] + red[2][2] + red[2][3];
    const float cnt = fmaxf(tc, 1.f);
    const float pm = tp / cnt, nm = tn / cnt;
    out[0] = pm + nm;
    out[1] = pm;
    out[2] = nm;
  }
}

extern "C" void kernel_launch(void* const* d_in, const int* in_sizes, int n_in,
                              void* d_out, int out_size, void* d_ws, size_t ws_size,
                              hipStream_t stream) {
  const float* batch = (const float*)d_in[0];
  const int* labels = (const int*)d_in[1];
  float* out = (float*)d_out;

  char* ws = (char*)d_ws;
  ushort* xp = (ushort*)ws;                       // N*D bf16 packed = 1 MB
  float* row_pos = (float*)(ws + (size_t)N * D * 2);
  float* row_neg = row_pos + N;
  float* row_valid = row_neg + N;

  k_norm<<<N / 16, 512, 0, stream>>>(batch, xp);
  k_mega<<<N / R, 512, 0, stream>>>(xp, labels, row_pos, row_neg, row_valid);
  k_final<<<1, 256, 0, stream>>>(row_pos, row_neg, row_valid, out);
}